// Round 5
// baseline (199.229 us; speedup 1.0000x reference)
//
#include <hip/hip_runtime.h>
#include <hip/hip_bf16.h>
#include <stdint.h>

// Problem constants
#define NB   32
#define CIN  128
#define HIN  56
#define WIN  56
#define KOUT 256
#define HOUT 54
#define WOUT 54
#define PQ   (HOUT*WOUT)     // 2916
#define NPIX (NB*PQ)         // 93312
#define KK   (CIN*9)         // 1152
#define HW   (HIN*WIN)       // 3136
#define TWN_FACTOR 0.05f

typedef short bf16x8 __attribute__((ext_vector_type(8)));   // 8 bf16 = 4 VGPRs
typedef float f32x4  __attribute__((ext_vector_type(4)));

// async global->LDS, 16B/lane; LDS dest = wave-uniform base + lane*16
__device__ __forceinline__ void glds16(const void* g, void* l) {
  __builtin_amdgcn_global_load_lds(
      (__attribute__((address_space(1))) void*)(g),
      (__attribute__((address_space(3))) void*)(l),
      16, 0, 0);
}

__device__ __forceinline__ unsigned pack_bf16(float a, float b) {
  return (unsigned)__bfloat16_as_ushort(__float2bfloat16(a)) |
         ((unsigned)__bfloat16_as_ushort(__float2bfloat16(b)) << 16);
}

// ---- fused prep: blocks [0,288) absmax(|w|); blocks [288,1856) x NCHW->NHWC bf16 ----
// phase 1 packs channel PAIRS into b32 LDS writes (16 b32 vs 32 scalar u16).
__global__ void prep_k(const float* __restrict__ x, const float4* __restrict__ w4,
                       float* __restrict__ amax, __hip_bfloat16* __restrict__ xt) {
  __shared__ __hip_bfloat16 tl[64 * 130 + 32];   // stride 130 (odd dwords)
  __shared__ float sm[4];
  int bid = blockIdx.x;
  int t   = threadIdx.x;

  if (bid < 288) {                               // absmax part (w = 1.18 MB)
    float4 v = w4[bid * 256 + t];
    float m = fmaxf(fmaxf(fabsf(v.x), fabsf(v.y)), fmaxf(fabsf(v.z), fabsf(v.w)));
    #pragma unroll
    for (int off = 32; off > 0; off >>= 1)
      m = fmaxf(m, __shfl_down(m, off));
    int lane = t & 63, wv = t >> 6;
    if (lane == 0) sm[wv] = m;
    __syncthreads();
    if (t == 0)                                  // ws poison 0xAA.. is a tiny negative float
      atomicMax(amax, fmaxf(fmaxf(sm[0], sm[1]), fmaxf(sm[2], sm[3])));
    return;
  }

  int b2 = bid - 288;                            // 0..1567
  int n  = b2 / 49, pc = b2 - n * 49;            // image, 64-pixel chunk
  const float* xb = x + (size_t)n * CIN * HW + pc * 64;
  int f4  = t & 15;                              // pixel group (4 px)
  int cp0 = t >> 4;                              // channel-pair base 0..15
  #pragma unroll
  for (int rd = 0; rd < 4; ++rd) {
    int cp = cp0 + rd * 16;                      // pair index 0..63 -> ch {2cp,2cp+1}
    const float* s0 = xb + (size_t)(2 * cp) * HW + f4 * 4;
    float4 v0 = *(const float4*)(s0);            // 256B/16-lane coalesced segments
    float4 v1 = *(const float4*)(s0 + HW);
    *(unsigned*)&tl[(f4 * 4 + 0) * 130 + 2 * cp] = pack_bf16(v0.x, v1.x);
    *(unsigned*)&tl[(f4 * 4 + 1) * 130 + 2 * cp] = pack_bf16(v0.y, v1.y);
    *(unsigned*)&tl[(f4 * 4 + 2) * 130 + 2 * cp] = pack_bf16(v0.z, v1.z);
    *(unsigned*)&tl[(f4 * 4 + 3) * 130 + 2 * cp] = pack_bf16(v0.w, v1.w);
  }
  __syncthreads();
  int cc = t & 15, p0 = t >> 4;                  // phase 2: b128 reads, 16B stores
  __hip_bfloat16* op = xt + ((size_t)n * HW + pc * 64) * CIN + cc * 8;
  #pragma unroll
  for (int p = p0; p < 64; p += 16)
    *(bf16x8*)(op + (size_t)p * CIN) = *(const bf16x8*)&tl[p * 130 + cc * 8];
}

// ---- quantize OIHW fp32 -> fragment-ordered qA[kc][256][8], kc = rs*16 + (c>>3) ----
__global__ void quant_k(const float* __restrict__ w, const float* __restrict__ amax,
                        __hip_bfloat16* __restrict__ qA) {
  float thr = TWN_FACTOR * (*amax);
  int t  = blockIdx.x * 256 + threadIdx.x;       // < 36864
  int kc = t >> 8, row = t & 255;
  int rs = kc >> 4, c0 = (kc & 15) << 3;
  bf16x8 q;
  #pragma unroll
  for (int j = 0; j < 8; ++j) {
    float v  = w[(size_t)(row * CIN + c0 + j) * 9 + rs];
    float qq = (v > thr) ? 1.f : ((v < -thr) ? -1.f : 0.f);
    q[j] = (short)__bfloat16_as_ushort(__float2bfloat16(qq));
  }
  *(bf16x8*)(qA + (size_t)t * 8) = q;            // 16B coalesced
}

// ---- implicit-GEMM conv: A reg-double-buffered; B LDS 3-buffer counted-vmcnt ----
// Per step t, issue order is fixed: [A(t+1) x8 b128] then [G(t+2) x4 glds].
// vmcnt ledger at step-t entry: [G(t)4, A(t)8, G(t+1)4] -> s_waitcnt vmcnt(4)
// drains exactly G(t)+A(t), BOTH issued a full step (~1500 cy) earlier. No load
// younger than one step is ever waited on; compute consumes A(t) from registers.
__global__ __launch_bounds__(256, 3) void conv_gemm(
    const __hip_bfloat16* __restrict__ xt,
    const __hip_bfloat16* __restrict__ qA,       // [144][256][8] fragment-ordered
    const float* __restrict__ bias,
    float* __restrict__ out) {
  __shared__ __hip_bfloat16 Bs[3][128 * 64];     // 3 x 16 KB, XOR-swizzled 16B chunks

  const int tid  = threadIdx.x;
  const int wave = tid >> 6;
  const int lane = tid & 63;
  const int quad = lane >> 4;
  const int l16  = lane & 15;

  // bijective XCD-chunked remap (nwg=1458 = 8*182 + 2)
  const int orig = blockIdx.x;
  const int xcd  = orig & 7;
  const int loc  = orig >> 3;
  const int bid  = (xcd < 2) ? xcd * 183 + loc
                             : 366 + (xcd - 2) * 182 + loc;

  const int ktile = bid & 1;
  const int ptile = bid >> 1;
  const int k0    = ktile * 128;
  const int pbase = ptile * 128;

  const int wm = (wave >> 1) * 64;               // k_out sub-tile
  const int wn = (wave & 1) * 64;                // pixel sub-tile

  // B staging: 4 glds16/wave/step; each glds = 8 rows x 8 chunks (1 KB).
  const int r8 = lane >> 3;
  const int ch = lane & 7;
  unsigned boffm[4];
  #pragma unroll
  for (int m = 0; m < 4; ++m) {
    int row  = wave * 32 + m * 8 + r8;
    int prow = pbase + row;
    int n = prow / PQ; int rm = prow - n * PQ;
    int p = rm / WOUT; int q = rm - p * WOUT;
    boffm[m] = (unsigned)(n * HW + p * WIN + q) * CIN + ((ch ^ (row & 7)) << 3);
  }

  // A fragment base offsets (elements): quad*2048 + row*8
  unsigned aoff[4];
  #pragma unroll
  for (int i = 0; i < 4; ++i)
    aoff[i] = (unsigned)(quad * 256 + (k0 + wm + i * 16 + l16)) * 8;

  f32x4 acc[4][4];
  #pragma unroll
  for (int i = 0; i < 4; ++i)
    #pragma unroll
    for (int j = 0; j < 4; ++j)
      acc[i][j] = (f32x4){0.f, 0.f, 0.f, 0.f};

  bf16x8 af[2][8];                               // A reg double-buffer [parity][h*4+i]

  // prologue (issue order pinned: G0, A0, G1 -> step-0 vmcnt(4) drains G0+A0)
  {
    char* bdst0 = (char*)Bs + wave * 4096;
    #pragma unroll
    for (int m = 0; m < 4; ++m)
      glds16(xt + boffm[m], bdst0 + m * 1024);             // G(0)
    __builtin_amdgcn_sched_barrier(0);
    #pragma unroll
    for (int h = 0; h < 2; ++h)
      #pragma unroll
      for (int i = 0; i < 4; ++i)
        af[0][h * 4 + i] = *(const bf16x8*)(qA + aoff[i] + (unsigned)h * 4 * 2048);  // A(0)
    __builtin_amdgcn_sched_barrier(0);
    char* bdst1 = (char*)Bs + 16384 + wave * 4096;
    #pragma unroll
    for (int m = 0; m < 4; ++m)
      glds16(xt + boffm[m] + 64u, bdst1 + m * 1024);       // G(1)
  }

  #pragma unroll
  for (int t = 0; t < 18; ++t) {
    if (t < 17) asm volatile("s_waitcnt vmcnt(4)" ::: "memory");
    else        asm volatile("s_waitcnt vmcnt(0)" ::: "memory");
    __builtin_amdgcn_s_barrier();
    __builtin_amdgcn_sched_barrier(0);

    // issue A(t+1) -> other register bank (static index: loop fully unrolled)
    if (t < 17) {
      const int tn = t + 1;
      const unsigned astep = ((unsigned)(tn >> 1) * 16 + (unsigned)(tn & 1) * 8) * 2048;
      #pragma unroll
      for (int h = 0; h < 2; ++h)
        #pragma unroll
        for (int i = 0; i < 4; ++i)
          af[tn & 1][h * 4 + i] =
              *(const bf16x8*)(qA + aoff[i] + astep + (unsigned)h * 4 * 2048);
    }
    __builtin_amdgcn_sched_barrier(0);

    // issue G(t+2) into buf (t+2)%3 (its readers finished at step t-1)
    if (t < 16) {
      const int tn  = t + 2;
      const int rsn = tn >> 1;
      const int rn  = rsn / 3, sn = rsn - rn * 3;
      const unsigned bst = (unsigned)((rn * WIN + sn) * CIN + (tn & 1) * 64);
      char* bdst = (char*)Bs + (unsigned)(tn % 3) * 16384 + wave * 4096;
      #pragma unroll
      for (int m = 0; m < 4; ++m)
        glds16(xt + boffm[m] + bst, bdst + m * 1024);
    }
    __builtin_amdgcn_sched_barrier(0);

    // compute on buf t%3 with A(t) from registers
    const char* bp = (const char*)Bs + (unsigned)(t % 3) * 16384;
    #pragma unroll
    for (int h = 0; h < 2; ++h) {
      bf16x8 bfr[4];
      #pragma unroll
      for (int i = 0; i < 4; ++i) {
        int row = wn + i * 16 + l16;
        bfr[i] = *(const bf16x8*)(bp + (row * 64 + (((h * 4 + quad) ^ (row & 7)) << 3)) * 2);
      }
      __builtin_amdgcn_s_setprio(1);
      #pragma unroll
      for (int i = 0; i < 4; ++i)
        #pragma unroll
        for (int j = 0; j < 4; ++j)
          acc[i][j] = __builtin_amdgcn_mfma_f32_16x16x32_bf16(af[t & 1][h * 4 + i], bfr[j],
                                                              acc[i][j], 0, 0, 0);
      __builtin_amdgcn_s_setprio(0);
    }
  }

  __syncthreads();                               // main loop done; repurpose Bs

  // ---- epilogue: per-wave LDS transpose -> k-major float4 stores (128B segments) ----
  {
    float* Sw = (float*)Bs + wave * 2048;        // 8 KB per wave
    const int ST  = 65;                          // padded row stride (dwords)
    const int rk  = lane >> 3;                   // 0..7  read row within half
    const int rp  = (lane & 7) * 4;              // 0..28 read pixel base
    const float4* b4 = (const float4*)bias;

    #pragma unroll
    for (int i = 0; i < 4; ++i) {
      float4 bv = b4[(k0 + wm + i * 16 + quad * 4) >> 2];
      #pragma unroll
      for (int j = 0; j < 4; ++j) {
        Sw[(quad * 4 + 0) * ST + j * 16 + l16] = acc[i][j][0] + bv.x;
        Sw[(quad * 4 + 1) * ST + j * 16 + l16] = acc[i][j][1] + bv.y;
        Sw[(quad * 4 + 2) * ST + j * 16 + l16] = acc[i][j][2] + bv.z;
        Sw[(quad * 4 + 3) * ST + j * 16 + l16] = acc[i][j][3] + bv.w;
      }
      asm volatile("s_waitcnt lgkmcnt(0)" ::: "memory");
      __builtin_amdgcn_sched_barrier(0);
      #pragma unroll
      for (int ri = 0; ri < 2; ++ri) {
        int klocal = ri * 8 + rk;
        int k = k0 + wm + i * 16 + klocal;
        #pragma unroll
        for (int cg = 0; cg < 2; ++cg) {
          int pixl = cg * 32 + rp;
          float4 v = *(const float4*)&Sw[klocal * ST + pixl];
          int pix = pbase + wn + pixl;
          int n = pix / PQ, pq = pix - n * PQ;   // PQ%4==0, pixl%4==0 -> no straddle
          *(float4*)(out + (size_t)n * (KOUT * PQ) + (size_t)k * PQ + pq) = v;
        }
      }
      asm volatile("s_waitcnt lgkmcnt(0)" ::: "memory");  // reads done before next chunk
      __builtin_amdgcn_sched_barrier(0);
    }
  }
}

extern "C" void kernel_launch(void* const* d_in, const int* in_sizes, int n_in,
                              void* d_out, int out_size, void* d_ws, size_t ws_size,
                              hipStream_t stream) {
  const float* x    = (const float*)d_in[0];
  const float* w    = (const float*)d_in[1];
  const float* bias = (const float*)d_in[2];
  float* out = (float*)d_out;

  // workspace: [0,4) amax float | [256,+25.7MB) xt bf16 | then qA bf16 (576KB)
  float* amax = (float*)d_ws;
  __hip_bfloat16* xt = (__hip_bfloat16*)((char*)d_ws + 256);
  __hip_bfloat16* qA = (__hip_bfloat16*)((char*)d_ws + 256 + (size_t)NB * HW * CIN * 2);

  prep_k  <<<dim3(1856), dim3(256), 0, stream>>>(x, (const float4*)w, amax, xt);
  quant_k <<<dim3(144),  dim3(256), 0, stream>>>(w, amax, qA);
  conv_gemm<<<dim3(1458), dim3(256), 0, stream>>>(xt, qA, bias, out);
}

// Round 8
// 195.724 us; speedup vs baseline: 1.0179x; 1.0179x over previous
//
#include <hip/hip_runtime.h>
#include <hip/hip_bf16.h>
#include <stdint.h>

// Problem constants
#define NB   32
#define CIN  128
#define HIN  56
#define WIN  56
#define KOUT 256
#define HOUT 54
#define WOUT 54
#define PQ   (HOUT*WOUT)     // 2916
#define NPIX (NB*PQ)         // 93312
#define KK   (CIN*9)         // 1152
#define HW   (HIN*WIN)       // 3136
#define TWN_FACTOR 0.05f

typedef short bf16x8 __attribute__((ext_vector_type(8)));   // 8 bf16 = 4 VGPRs
typedef float f32x4  __attribute__((ext_vector_type(4)));

// async global->LDS, 16B/lane; LDS dest = wave-uniform base + lane*16
__device__ __forceinline__ void glds16(const void* g, void* l) {
  __builtin_amdgcn_global_load_lds(
      (__attribute__((address_space(1))) void*)(g),
      (__attribute__((address_space(3))) void*)(l),
      16, 0, 0);
}

__device__ __forceinline__ unsigned pack_bf16(float a, float b) {
  return (unsigned)__bfloat16_as_ushort(__float2bfloat16(a)) |
         ((unsigned)__bfloat16_as_ushort(__float2bfloat16(b)) << 16);
}

// ---- fused prep: blocks [0,288) absmax(|w|); blocks [288,1856) x NCHW->NHWC bf16 ----
__global__ void prep_k(const float* __restrict__ x, const float4* __restrict__ w4,
                       float* __restrict__ amax, __hip_bfloat16* __restrict__ xt) {
  __shared__ __hip_bfloat16 tl[64 * 130 + 32];   // stride 130 (odd dwords)
  __shared__ float sm[4];
  int bid = blockIdx.x;
  int t   = threadIdx.x;

  if (bid < 288) {                               // absmax part (w = 1.18 MB)
    float4 v = w4[bid * 256 + t];
    float m = fmaxf(fmaxf(fabsf(v.x), fabsf(v.y)), fmaxf(fabsf(v.z), fabsf(v.w)));
    #pragma unroll
    for (int off = 32; off > 0; off >>= 1)
      m = fmaxf(m, __shfl_down(m, off));
    int lane = t & 63, wv = t >> 6;
    if (lane == 0) sm[wv] = m;
    __syncthreads();
    if (t == 0)                                  // ws poison 0xAA.. is a tiny negative float
      atomicMax(amax, fmaxf(fmaxf(sm[0], sm[1]), fmaxf(sm[2], sm[3])));
    return;
  }

  int b2 = bid - 288;                            // 0..1567
  int n  = b2 / 49, pc = b2 - n * 49;            // image, 64-pixel chunk
  const float* xb = x + (size_t)n * CIN * HW + pc * 64;
  int f4  = t & 15;                              // pixel group (4 px)
  int cp0 = t >> 4;                              // channel-pair base 0..15
  #pragma unroll
  for (int rd = 0; rd < 4; ++rd) {
    int cp = cp0 + rd * 16;                      // pair index 0..63 -> ch {2cp,2cp+1}
    const float* s0 = xb + (size_t)(2 * cp) * HW + f4 * 4;
    float4 v0 = *(const float4*)(s0);            // 256B/16-lane coalesced segments
    float4 v1 = *(const float4*)(s0 + HW);
    *(unsigned*)&tl[(f4 * 4 + 0) * 130 + 2 * cp] = pack_bf16(v0.x, v1.x);
    *(unsigned*)&tl[(f4 * 4 + 1) * 130 + 2 * cp] = pack_bf16(v0.y, v1.y);
    *(unsigned*)&tl[(f4 * 4 + 2) * 130 + 2 * cp] = pack_bf16(v0.z, v1.z);
    *(unsigned*)&tl[(f4 * 4 + 3) * 130 + 2 * cp] = pack_bf16(v0.w, v1.w);
  }
  __syncthreads();
  int cc = t & 15, p0 = t >> 4;                  // phase 2: b128 reads, 16B stores
  __hip_bfloat16* op = xt + ((size_t)n * HW + pc * 64) * CIN + cc * 8;
  #pragma unroll
  for (int p = p0; p < 64; p += 16)
    *(bf16x8*)(op + (size_t)p * CIN) = *(const bf16x8*)&tl[p * 130 + cc * 8];
}

// ---- quantize OIHW fp32 -> fragment-ordered qA[kc][256][8], kc = rs*16 + (c>>3) ----
__global__ void quant_k(const float* __restrict__ w, const float* __restrict__ amax,
                        __hip_bfloat16* __restrict__ qA) {
  float thr = TWN_FACTOR * (*amax);
  int t  = blockIdx.x * 256 + threadIdx.x;       // < 36864
  int kc = t >> 8, row = t & 255;
  int rs = kc >> 4, c0 = (kc & 15) << 3;
  bf16x8 q;
  #pragma unroll
  for (int j = 0; j < 8; ++j) {
    float v  = w[(size_t)(row * CIN + c0 + j) * 9 + rs];
    float qq = (v > thr) ? 1.f : ((v < -thr) ? -1.f : 0.f);
    q[j] = (short)__bfloat16_as_ushort(__float2bfloat16(qq));
  }
  *(bf16x8*)(qA + (size_t)t * 8) = q;            // 16B coalesced
}

// ---- implicit-GEMM conv: 2-buffer LDS (32 KB), guide-verified 2-phase template ----
// Schedule per step t (guide §5.5 T3 "minimum 2-phase", __syncthreads-fenced):
//   __syncthreads()  -- drains G(t)/A(t) (issued a FULL step earlier) + full fence
//   issue G(t+1) -> buf (t+1)&1   (readers finished at step t-1, before the sync)
//   issue A(t+1) -> af[(t+1)&1]
//   compute buf t&1 with af[t&1]  (everything consumed is step-old, zero wait)
// Nothing issued in step t is waited on in step t. __syncthreads (not raw
// s_barrier) so the compiler has a true memory fence -- R6's raw-barrier
// variant miscompared (absmax 28.6) despite a sound hand-ledger; this is the
// same schedule with canonical fencing. No setprio (m190).
__global__ __launch_bounds__(256, 3) void conv_gemm(
    const __hip_bfloat16* __restrict__ xt,
    const __hip_bfloat16* __restrict__ qA,       // [144][256][8] fragment-ordered
    const float* __restrict__ bias,
    float* __restrict__ out) {
  __shared__ __hip_bfloat16 Bs[2][128 * 64];     // 2 x 16 KB, XOR-swizzled 16B chunks

  const int tid  = threadIdx.x;
  const int wave = tid >> 6;
  const int lane = tid & 63;
  const int quad = lane >> 4;
  const int l16  = lane & 15;

  // bijective XCD-chunked remap (nwg=1458 = 8*182 + 2)
  const int orig = blockIdx.x;
  const int xcd  = orig & 7;
  const int loc  = orig >> 3;
  const int bid  = (xcd < 2) ? xcd * 183 + loc
                             : 366 + (xcd - 2) * 182 + loc;

  const int ktile = bid & 1;
  const int ptile = bid >> 1;
  const int k0    = ktile * 128;
  const int pbase = ptile * 128;

  const int wm = (wave >> 1) * 64;               // k_out sub-tile
  const int wn = (wave & 1) * 64;                // pixel sub-tile

  // B staging: 4 glds16/wave/step; each glds = 8 rows x 8 chunks (1 KB).
  const int r8 = lane >> 3;
  const int ch = lane & 7;
  unsigned boffm[4];
  #pragma unroll
  for (int m = 0; m < 4; ++m) {
    int row  = wave * 32 + m * 8 + r8;
    int prow = pbase + row;
    int n = prow / PQ; int rm = prow - n * PQ;
    int p = rm / WOUT; int q = rm - p * WOUT;
    boffm[m] = (unsigned)(n * HW + p * WIN + q) * CIN + ((ch ^ (row & 7)) << 3);
  }

  // A fragment base offsets (elements): quad*2048 + row*8
  unsigned aoff[4];
  #pragma unroll
  for (int i = 0; i < 4; ++i)
    aoff[i] = (unsigned)(quad * 256 + (k0 + wm + i * 16 + l16)) * 8;

  f32x4 acc[4][4];
  #pragma unroll
  for (int i = 0; i < 4; ++i)
    #pragma unroll
    for (int j = 0; j < 4; ++j)
      acc[i][j] = (f32x4){0.f, 0.f, 0.f, 0.f};

  bf16x8 af[2][8];                               // A reg double-buffer [parity][h*4+i]

  // prologue: G(0) into buf 0, A(0) into af[0]; drained by step-0 __syncthreads
  {
    char* bdst0 = (char*)Bs + wave * 4096;
    #pragma unroll
    for (int m = 0; m < 4; ++m)
      glds16(xt + boffm[m], bdst0 + m * 1024);             // G(0)
    #pragma unroll
    for (int h = 0; h < 2; ++h)
      #pragma unroll
      for (int i = 0; i < 4; ++i)
        af[0][h * 4 + i] = *(const bf16x8*)(qA + aoff[i] + (unsigned)h * 4 * 2048);  // A(0)
  }

  #pragma unroll
  for (int t = 0; t < 18; ++t) {
    // Full fence + drain of G(t)/A(t) (both issued one whole step earlier).
    __syncthreads();

    // issue G(t+1) FIRST (max lead time) into buf (t+1)&1
    if (t < 17) {
      const int tn  = t + 1;
      const int rsn = tn >> 1;
      const int rn  = rsn / 3, sn = rsn - rn * 3;
      const unsigned bst = (unsigned)((rn * WIN + sn) * CIN + (tn & 1) * 64);
      char* bdst = (char*)Bs + (unsigned)(tn & 1) * 16384 + wave * 4096;
      #pragma unroll
      for (int m = 0; m < 4; ++m)
        glds16(xt + boffm[m] + bst, bdst + m * 1024);
    }
    __builtin_amdgcn_sched_barrier(0);

    // issue A(t+1) -> other register bank (fully unrolled, static index)
    if (t < 17) {
      const int tn = t + 1;
      const unsigned astep = ((unsigned)(tn >> 1) * 16 + (unsigned)(tn & 1) * 8) * 2048;
      #pragma unroll
      for (int h = 0; h < 2; ++h)
        #pragma unroll
        for (int i = 0; i < 4; ++i)
          af[tn & 1][h * 4 + i] =
              *(const bf16x8*)(qA + aoff[i] + astep + (unsigned)h * 4 * 2048);
    }
    __builtin_amdgcn_sched_barrier(0);

    // compute on buf t&1 with A(t) from registers
    const char* bp = (const char*)Bs + (unsigned)(t & 1) * 16384;
    #pragma unroll
    for (int h = 0; h < 2; ++h) {
      bf16x8 bfr[4];
      #pragma unroll
      for (int i = 0; i < 4; ++i) {
        int row = wn + i * 16 + l16;
        bfr[i] = *(const bf16x8*)(bp + (row * 64 + (((h * 4 + quad) ^ (row & 7)) << 3)) * 2);
      }
      #pragma unroll
      for (int i = 0; i < 4; ++i)
        #pragma unroll
        for (int j = 0; j < 4; ++j)
          acc[i][j] = __builtin_amdgcn_mfma_f32_16x16x32_bf16(af[t & 1][h * 4 + i], bfr[j],
                                                              acc[i][j], 0, 0, 0);
    }
  }

  __syncthreads();                               // main loop done; repurpose Bs

  // ---- epilogue: per-wave LDS transpose -> k-major float4 stores (128B segments) ----
  // wave-private 8 KB regions; 4 x 8 KB = 32 KB == sizeof(Bs).
  {
    float* Sw = (float*)Bs + wave * 2048;        // 8 KB per wave
    const int ST  = 65;                          // padded row stride (dwords)
    const int rk  = lane >> 3;                   // 0..7  read row within half
    const int rp  = (lane & 7) * 4;              // 0..28 read pixel base
    const float4* b4 = (const float4*)bias;

    #pragma unroll
    for (int i = 0; i < 4; ++i) {
      float4 bv = b4[(k0 + wm + i * 16 + quad * 4) >> 2];
      #pragma unroll
      for (int j = 0; j < 4; ++j) {
        Sw[(quad * 4 + 0) * ST + j * 16 + l16] = acc[i][j][0] + bv.x;
        Sw[(quad * 4 + 1) * ST + j * 16 + l16] = acc[i][j][1] + bv.y;
        Sw[(quad * 4 + 2) * ST + j * 16 + l16] = acc[i][j][2] + bv.z;
        Sw[(quad * 4 + 3) * ST + j * 16 + l16] = acc[i][j][3] + bv.w;
      }
      asm volatile("s_waitcnt lgkmcnt(0)" ::: "memory");
      __builtin_amdgcn_sched_barrier(0);
      #pragma unroll
      for (int ri = 0; ri < 2; ++ri) {
        int klocal = ri * 8 + rk;
        int k = k0 + wm + i * 16 + klocal;
        #pragma unroll
        for (int cg = 0; cg < 2; ++cg) {
          int pixl = cg * 32 + rp;
          float4 v = *(const float4*)&Sw[klocal * ST + pixl];
          int pix = pbase + wn + pixl;
          int n = pix / PQ, pq = pix - n * PQ;   // PQ%4==0, pixl%4==0 -> no straddle
          *(float4*)(out + (size_t)n * (KOUT * PQ) + (size_t)k * PQ + pq) = v;
        }
      }
      asm volatile("s_waitcnt lgkmcnt(0)" ::: "memory");  // reads done before next chunk
      __builtin_amdgcn_sched_barrier(0);
    }
  }
}

extern "C" void kernel_launch(void* const* d_in, const int* in_sizes, int n_in,
                              void* d_out, int out_size, void* d_ws, size_t ws_size,
                              hipStream_t stream) {
  const float* x    = (const float*)d_in[0];
  const float* w    = (const float*)d_in[1];
  const float* bias = (const float*)d_in[2];
  float* out = (float*)d_out;

  // workspace: [0,4) amax float | [256,+25.7MB) xt bf16 | then qA bf16 (576KB)
  float* amax = (float*)d_ws;
  __hip_bfloat16* xt = (__hip_bfloat16*)((char*)d_ws + 256);
  __hip_bfloat16* qA = (__hip_bfloat16*)((char*)d_ws + 256 + (size_t)NB * HW * CIN * 2);

  prep_k  <<<dim3(1856), dim3(256), 0, stream>>>(x, (const float4*)w, amax, xt);
  quant_k <<<dim3(144),  dim3(256), 0, stream>>>(w, amax, qA);
  conv_gemm<<<dim3(1458), dim3(256), 0, stream>>>(xt, qA, bias, out);
}